// Round 12
// baseline (102.630 us; speedup 1.0000x reference)
//
#include <hip/hip_runtime.h>
#include <hip/hip_bf16.h>

// Problem constants
#define B_ 4
#define C_ 512
#define N_ 2048
#define H_ 8
#define D_ 64
#define O3_ 1536   // 3*C
#define SPLIT 2
#define JTN 16     // (N_/64)/SPLIT

typedef __bf16 bf16x8 __attribute__((ext_vector_type(8)));
typedef float f32x4 __attribute__((ext_vector_type(4)));
typedef unsigned short ushort_t;

// q pre-scale: d^-0.5 (=0.125) * log2(e) so softmax uses exp2 directly
#define QSCALE 0.1803368801111137f

__device__ inline ushort_t f2b(float f) {
    __hip_bfloat16 h = __float2bfloat16(f);
    return *reinterpret_cast<ushort_t*>(&h);
}
__device__ inline float b2f(ushort_t u) {
    unsigned v = ((unsigned)u) << 16;
    return *reinterpret_cast<float*>(&v);
}
__device__ inline unsigned pkbf(float a, float b) {
    return (unsigned)f2b(a) | ((unsigned)f2b(b) << 16);
}
// CDNA4 row-swap permlanes (VALU pipe). Combined pl32+pl16 transform maps the
// swapped-QK^T P layout (lane: q=low, keys hi*4+r per nt) onto the MFMA frag
// layout (q=low, keys hi*8..+7 per 32-key slice). VERIFIED passing ONLY under
// a 256-VGPR budget (R10); FAILS under a 128-VGPR launch-bounds cap
// (R8 (256,4), R11 (512,4)) — allocator pressure corrupts the "+v" asm pairs.
__device__ inline void pl32swap(unsigned& a, unsigned& b) {
    asm volatile("v_permlane32_swap_b32 %0, %1" : "+v"(a), "+v"(b));
}
__device__ inline void pl16swap(unsigned& a, unsigned& b) {
    asm volatile("v_permlane16_swap_b32 %0, %1" : "+v"(a), "+v"(b));
}

// async global->LDS DMA, 16B per lane; LDS dest = wave-uniform base + lane*16
__device__ inline void gload16(const ushort_t* g, ushort_t* l) {
    __builtin_amdgcn_global_load_lds(
        (const __attribute__((address_space(1))) unsigned int*)g,
        (__attribute__((address_space(3))) unsigned int*)l, 16, 0, 0);
}

// ---------------------------------------------------------------------------
// Kernel 1: LN (blocks 0..255) + weight fp32->bf16 convert (blocks 256..1023)
// LN keeps x in registers between the moment pass and the normalize pass.
// ---------------------------------------------------------------------------
__global__ __launch_bounds__(256) void k_pre(const float* __restrict__ x,
                                             const float* __restrict__ g,
                                             ushort_t* __restrict__ xnT,
                                             const float* __restrict__ wqkv,
                                             const float* __restrict__ wout,
                                             ushort_t* __restrict__ wqkv_b,
                                             ushort_t* __restrict__ wout_b) {
    if (blockIdx.x >= 256) {
        int i = (blockIdx.x - 256) * 256 + threadIdx.x;   // 0..196607
        float4 a = reinterpret_cast<const float4*>(wqkv)[i];
        ushort4 o;
        o.x = f2b(a.x); o.y = f2b(a.y); o.z = f2b(a.z); o.w = f2b(a.w);
        reinterpret_cast<ushort4*>(wqkv_b)[i] = o;
        if (i < 65536) {
            float4 c = reinterpret_cast<const float4*>(wout)[i];
            ushort4 oc;
            oc.x = f2b(c.x); oc.y = f2b(c.y); oc.z = f2b(c.z); oc.w = f2b(c.w);
            reinterpret_cast<ushort4*>(wout_b)[i] = oc;
        }
        return;
    }

    int bid = blockIdx.x;
    int b  = bid >> 6;
    int j0 = (bid & 63) * 32;
    int t  = threadIdx.x;

    __shared__ float s_red[8][32];
    __shared__ float s_red2[8][32];
    __shared__ float s_mean[32], s_rstd[32];
    __shared__ float s_g[C_];
    __shared__ __align__(16) ushort_t s_t[32][C_ + 2];

    for (int i = t; i < C_; i += 256) s_g[i] = g[i];

    int jl = t & 31, cg = t >> 5;
    const float* xb = x + (size_t)b * C_ * N_;

    float xv[64];
    float sum = 0.f, sq = 0.f;
#pragma unroll
    for (int i = 0; i < 64; ++i) {
        float v = xb[(size_t)(cg * 64 + i) * N_ + j0 + jl];
        xv[i] = v;
        sum += v; sq += v * v;
    }
    s_red[cg][jl] = sum; s_red2[cg][jl] = sq;
    __syncthreads();
    if (t < 32) {
        float s = 0.f, q = 0.f;
#pragma unroll
        for (int i = 0; i < 8; ++i) { s += s_red[i][t]; q += s_red2[i][t]; }
        float mean = s * (1.0f / C_);
        float var  = q * (1.0f / C_) - mean * mean;
        s_mean[t] = mean;
        s_rstd[t] = rsqrtf(var + 1e-5f);
    }
    __syncthreads();

    float mean = s_mean[jl], rstd = s_rstd[jl];
#pragma unroll
    for (int i = 0; i < 64; ++i) {
        int c = cg * 64 + i;
        s_t[jl][c] = f2b((xv[i] - mean) * rstd * s_g[c]);
    }
    __syncthreads();

    for (int jr = 0; jr < 32; ++jr) {
        unsigned val = *reinterpret_cast<const unsigned*>(&s_t[jr][t * 2]);
        *reinterpret_cast<unsigned*>(
            &xnT[((size_t)(b * N_ + j0 + jr)) * C_ + t * 2]) = val;
    }
}

// ---------------------------------------------------------------------------
// GEMM (m97 structure): C[o][j] = sum_c A[o][c] * BT[b][j][c]
// global_load_lds staging (16B), linear LDS, source-XOR-swizzle + swizzled
// b128 fragment reads. XCD-chunked block swizzle (bijective, grid%8==0).
// ---------------------------------------------------------------------------
template <int MODE>
__global__ __launch_bounds__(256) void k_gemm(const ushort_t* __restrict__ A,
                                              const ushort_t* __restrict__ Bt,
                                              ushort_t* __restrict__ qT,
                                              ushort_t* __restrict__ kT,
                                              ushort_t* __restrict__ vv,
                                              float* __restrict__ out,
                                              const float* __restrict__ b_out) {
    constexpr int M = (MODE == 0) ? O3_ : C_;
    constexpr int K = C_;
    constexpr int NMT = M / 128;
    constexpr int NWG = B_ * NMT * 16;          // 768 or 256; % 8 == 0

    int bid  = blockIdx.x;
    int sbid = (bid & 7) * (NWG / 8) + (bid >> 3);   // XCD-chunked, bijective
    int b    = sbid / (NMT * 16);
    int rem  = sbid % (NMT * 16);
    int mt0  = (rem / 16) * 128;
    int nt0  = (rem % 16) * 128;

    int t = threadIdx.x;
    int w = t >> 6, lane = t & 63;
    int wm = (w >> 1) * 64, wn = (w & 1) * 64;
    int low = lane & 15, hi = lane >> 4;

    __shared__ __align__(16) ushort_t sA[128][64];
    __shared__ __align__(16) ushort_t sB[128][64];

    const ushort_t* Bb = Bt + (size_t)b * N_ * K;

    int srow = lane >> 3;
    int sseg = (lane & 7) ^ srow;
    const ushort_t* Ag = A  + (size_t)(mt0 + w * 32 + srow) * K + sseg * 8;
    const ushort_t* Bg = Bb + (size_t)(nt0 + w * 32 + srow) * K + sseg * 8;

    f32x4 acc[4][4] = {};

    for (int k0 = 0; k0 < K; k0 += 64) {
#pragma unroll
        for (int i = 0; i < 4; ++i) {
            gload16(Ag + (size_t)(i * 8) * K + k0, &sA[w * 32 + i * 8][0]);
            gload16(Bg + (size_t)(i * 8) * K + k0, &sB[w * 32 + i * 8][0]);
        }
        asm volatile("s_waitcnt vmcnt(0)" ::: "memory");
        __syncthreads();
#pragma unroll
        for (int kk = 0; kk < 64; kk += 32) {
            bf16x8 af[4], bfr[4];
#pragma unroll
            for (int mt = 0; mt < 4; ++mt) {
                int cseg = ((kk >> 3) + hi) ^ (low & 7);
                af[mt] = *reinterpret_cast<const bf16x8*>(
                    &sA[wm + mt * 16 + low][cseg * 8]);
            }
#pragma unroll
            for (int nt = 0; nt < 4; ++nt) {
                int cseg = ((kk >> 3) + hi) ^ (low & 7);
                bfr[nt] = *reinterpret_cast<const bf16x8*>(
                    &sB[wn + nt * 16 + low][cseg * 8]);
            }
#pragma unroll
            for (int mt = 0; mt < 4; ++mt)
#pragma unroll
                for (int nt = 0; nt < 4; ++nt)
                    acc[mt][nt] = __builtin_amdgcn_mfma_f32_16x16x32_bf16(
                        af[mt], bfr[nt], acc[mt][nt], 0, 0, 0);
        }
        __syncthreads();
    }

#pragma unroll
    for (int mt = 0; mt < 4; ++mt)
#pragma unroll
        for (int nt = 0; nt < 4; ++nt) {
            int m0 = mt0 + wm + mt * 16 + hi * 4;
            int j  = nt0 + wn + nt * 16 + low;
            if constexpr (MODE == 0) {
                if (m0 < 512) {
                    ushort4 pk;
                    pk.x = f2b(acc[mt][nt][0] * QSCALE);
                    pk.y = f2b(acc[mt][nt][1] * QSCALE);
                    pk.z = f2b(acc[mt][nt][2] * QSCALE);
                    pk.w = f2b(acc[mt][nt][3] * QSCALE);
                    *reinterpret_cast<ushort4*>(
                        &qT[(((size_t)(b * H_ + (m0 >> 6)) * N_) + j) * D_ +
                            (m0 & 63)]) = pk;
                } else if (m0 < 1024) {
                    int mm = m0 - 512;
                    ushort4 pk;
                    pk.x = f2b(acc[mt][nt][0]);
                    pk.y = f2b(acc[mt][nt][1]);
                    pk.z = f2b(acc[mt][nt][2]);
                    pk.w = f2b(acc[mt][nt][3]);
                    *reinterpret_cast<ushort4*>(
                        &kT[(((size_t)(b * H_ + (mm >> 6)) * N_) + j) * D_ +
                            (mm & 63)]) = pk;
                } else {
                    int mm0 = m0 - 1024;
#pragma unroll
                    for (int r = 0; r < 4; ++r)
                        vv[(((size_t)(b * H_ + (mm0 >> 6)) * D_) +
                            ((mm0 & 63) + r)) * N_ + j] = f2b(acc[mt][nt][r]);
                }
            } else {
#pragma unroll
                for (int r = 0; r < 4; ++r)
                    out[((size_t)(b * C_ + m0 + r)) * N_ + j] =
                        acc[mt][nt][r] + b_out[m0 + r];
            }
        }
}

// ---------------------------------------------------------------------------
// Attention v8b: identical to R11's v8 EXCEPT __launch_bounds__(512, 2)
// (VGPR budget 256, not 128). Hypothesis test: permlane asm passes under
// a 256-VGPR budget (R10) and fails under a 128 cap (R8/R11). Natural
// footprint est. 60-100 VGPR -> HW residency should stay 2 blocks/CU.
// ---------------------------------------------------------------------------
__global__ __launch_bounds__(512, 2) void k_attn(const ushort_t* __restrict__ qT,
                                                 const ushort_t* __restrict__ kT,
                                                 const ushort_t* __restrict__ vv,
                                                 ushort_t* __restrict__ O0,
                                                 ushort_t* __restrict__ O1,
                                                 float* __restrict__ Lp) {
    int bid  = blockIdx.x;
    int sbid = ((bid & 7) << 6) | (bid >> 3);   // XCD swizzle over 512 blocks
    int it256 = sbid & 7;
    int s     = (sbid >> 3) & 1;
    int h     = (sbid >> 4) & 7;
    int b     = sbid >> 7;
    int i0    = it256 * 256;
    int t = threadIdx.x, w = t >> 6, lane = t & 63;
    int low = lane & 15, hi = lane >> 4;

    __shared__ ushort_t sK[2][64][64];          // linear, seg-swizzled content
    __shared__ ushort_t sV[2][64][64];          // [d][key]

    const ushort_t* qb = qT + ((size_t)(b * H_ + h)) * N_ * D_;
    const ushort_t* kb = kT + ((size_t)(b * H_ + h)) * N_ * D_;
    const ushort_t* vb = vv + ((size_t)(b * H_ + h)) * D_ * N_;

    int srow = lane >> 3;
    int sseg = (lane & 7) ^ srow;
    const ushort_t* kg = kb + (size_t)(w * 8 + srow) * D_ + sseg * 8;
    const ushort_t* vg = vb + (size_t)(w * 8 + srow) * N_ + sseg * 8;

    // Q fragments: wave w owns q-rows w*32..w*32+31
    bf16x8 qf[2][2];
#pragma unroll
    for (int mt = 0; mt < 2; ++mt)
#pragma unroll
        for (int kx = 0; kx < 2; ++kx)
            qf[mt][kx] = *reinterpret_cast<const bf16x8*>(
                &qb[(size_t)(i0 + w * 32 + mt * 16 + low) * D_ + kx * 32 + hi * 8]);

    // prologue: stage tile 0 into buf 0
    {
        int j0 = s * JTN * 64;
        gload16(kg + (size_t)j0 * D_, &sK[0][w * 8][0]);
        gload16(vg + j0,              &sV[0][w * 8][0]);
    }
    asm volatile("s_waitcnt vmcnt(0)" ::: "memory");
    __syncthreads();

    f32x4 oacc[2][4] = {};
    float lp0 = 0.f, lp1 = 0.f;
    int sw = (low & 7) * 8;   // fragment-read XOR base (shorts)

    int buf = 0;
    for (int jj = 0; jj < JTN; ++jj) {
        // prefetch next tile into the other buffer (async DMA)
        if (jj + 1 < JTN) {
            int j0n = (s * JTN + jj + 1) * 64;
            gload16(kg + (size_t)j0n * D_, &sK[buf ^ 1][w * 8][0]);
            gload16(vg + j0n,              &sV[buf ^ 1][w * 8][0]);
        }

        // S^T = K Q^T : rows = keys (64), cols = this wave's 32 q
        f32x4 sacc[2][4] = {};   // [mt][nt]: key = nt*16+hi*4+r, q = mt*16+low
#pragma unroll
        for (int kx = 0; kx < 2; ++kx) {
            bf16x8 kfx[4];
#pragma unroll
            for (int nt = 0; nt < 4; ++nt)
                kfx[nt] = *reinterpret_cast<const bf16x8*>(
                    &sK[buf][nt * 16 + low][((kx * 4 + hi) * 8) ^ sw]);
#pragma unroll
            for (int mt = 0; mt < 2; ++mt)
#pragma unroll
                for (int nt = 0; nt < 4; ++nt)
                    sacc[mt][nt] = __builtin_amdgcn_mfma_f32_16x16x32_bf16(
                        kfx[nt], qf[mt][kx], sacc[mt][nt], 0, 0, 0);
        }

        // V fragments: row = d = dt*16+low, k = key = kx*32+hi*8..+7
        bf16x8 vf[2][4];
#pragma unroll
        for (int kx = 0; kx < 2; ++kx)
#pragma unroll
            for (int dt = 0; dt < 4; ++dt)
                vf[kx][dt] = *reinterpret_cast<const bf16x8*>(
                    &sV[buf][dt * 16 + low][((kx * 4 + hi) * 8) ^ sw]);

        // per q-16-block: exp2 -> pack bf16 -> permlane -> PV (P in-register)
#pragma unroll
        for (int mt = 0; mt < 2; ++mt) {
            float p[4][4];
#pragma unroll
            for (int nt = 0; nt < 4; ++nt)
#pragma unroll
                for (int r = 0; r < 4; ++r)
                    p[nt][r] = __builtin_amdgcn_exp2f(sacc[mt][nt][r]);
            float ls = ((p[0][0] + p[0][1]) + (p[0][2] + p[0][3])) +
                       ((p[1][0] + p[1][1]) + (p[1][2] + p[1][3])) +
                       ((p[2][0] + p[2][1]) + (p[2][2] + p[2][3])) +
                       ((p[3][0] + p[3][1]) + (p[3][2] + p[3][3]));
            if (mt == 0) lp0 += ls; else lp1 += ls;
#pragma unroll
            for (int kx = 0; kx < 2; ++kx) {
                unsigned a0 = pkbf(p[2 * kx][0],     p[2 * kx][1]);
                unsigned a1 = pkbf(p[2 * kx][2],     p[2 * kx][3]);
                unsigned b0 = pkbf(p[2 * kx + 1][0], p[2 * kx + 1][1]);
                unsigned b1 = pkbf(p[2 * kx + 1][2], p[2 * kx + 1][3]);
                pl32swap(a0, b0);
                pl16swap(a0, b0);
                pl32swap(a1, b1);
                pl16swap(a1, b1);
                unsigned tw[4] = {a0, a1, b0, b1};
                bf16x8 pb = *reinterpret_cast<const bf16x8*>(tw);
                // A = P (rows=q), B = V (cols=d): same epilogue as v4
#pragma unroll
                for (int dt = 0; dt < 4; ++dt)
                    oacc[mt][dt] = __builtin_amdgcn_mfma_f32_16x16x32_bf16(
                        pb, vf[kx][dt], oacc[mt][dt], 0, 0, 0);
            }
        }

        // own prefetch DMA landed (issued a full compute phase ago), then sync
        asm volatile("s_waitcnt vmcnt(0)" ::: "memory");
        __syncthreads();
        buf ^= 1;
    }

    // reduce row-sum partials across the 4 hi-groups
    lp0 += __shfl_xor(lp0, 16); lp0 += __shfl_xor(lp0, 32);
    lp1 += __shfl_xor(lp1, 16); lp1 += __shfl_xor(lp1, 32);

    float* lrow = Lp + ((size_t)((s * B_ + b) * H_ + h)) * N_ + i0 + w * 32;
    if (lane < 16) {
        lrow[low]      = lp0;
        lrow[16 + low] = lp1;
    }

    // partial O (unnormalized) in attnT layout [b][i][h*64+d], bf16
    ushort_t* op = (s == 0 ? O0 : O1) +
                   ((size_t)(b * N_ + i0 + w * 32)) * C_ + h * D_;
#pragma unroll
    for (int mt = 0; mt < 2; ++mt)
#pragma unroll
        for (int dt = 0; dt < 4; ++dt)
#pragma unroll
            for (int r = 0; r < 4; ++r)
                op[(size_t)(mt * 16 + hi * 4 + r) * C_ + dt * 16 + low] =
                    f2b(oacc[mt][dt][r]);
}

// ---------------------------------------------------------------------------
// Combine: attnT = (O0 + O1) / (l0 + l1)   (in-place on O0 == attnT)
// ---------------------------------------------------------------------------
__global__ __launch_bounds__(256) void k_comb(const ushort_t* __restrict__ O1,
                                              const float* __restrict__ Lp,
                                              ushort_t* __restrict__ attnT) {
    int tid = blockIdx.x * 256 + threadIdx.x;   // 1,048,576 total
    int d4 = (tid & 15) * 4;
    int i  = (tid >> 4) & (N_ - 1);
    int bh = tid >> 15;                          // 0..31
    int b = bh >> 3, h = bh & 7;
    size_t idx = ((size_t)(b * N_ + i)) * C_ + h * D_ + d4;
    ushort4 a0 = *reinterpret_cast<const ushort4*>(&attnT[idx]);
    ushort4 a1 = *reinterpret_cast<const ushort4*>(&O1[idx]);
    float l = Lp[(size_t)bh * N_ + i] + Lp[(size_t)(B_ * H_ + bh) * N_ + i];
    float linv = 1.0f / l;
    ushort4 o;
    o.x = f2b((b2f(a0.x) + b2f(a1.x)) * linv);
    o.y = f2b((b2f(a0.y) + b2f(a1.y)) * linv);
    o.z = f2b((b2f(a0.z) + b2f(a1.z)) * linv);
    o.w = f2b((b2f(a0.w) + b2f(a1.w)) * linv);
    *reinterpret_cast<ushort4*>(&attnT[idx]) = o;
}

// ---------------------------------------------------------------------------
// Launch
// ---------------------------------------------------------------------------
extern "C" void kernel_launch(void* const* d_in, const int* in_sizes, int n_in,
                              void* d_out, int out_size, void* d_ws, size_t ws_size,
                              hipStream_t stream) {
    const float* x    = (const float*)d_in[0];
    const float* g    = (const float*)d_in[1];
    const float* wqkv = (const float*)d_in[2];
    const float* wout = (const float*)d_in[3];
    const float* bout = (const float*)d_in[4];
    float* out = (float*)d_out;

    char* ws = (char*)d_ws;
    ushort_t* xnT    = (ushort_t*)(ws);                            // 8 MiB (O1)
    ushort_t* qT     = (ushort_t*)(ws + (size_t)8  * 1024 * 1024); // 8 MiB
    ushort_t* kT     = (ushort_t*)(ws + (size_t)16 * 1024 * 1024); // 8 MiB
    ushort_t* vv     = (ushort_t*)(ws + (size_t)24 * 1024 * 1024); // 8 MiB
    ushort_t* attnT  = (ushort_t*)(ws + (size_t)32 * 1024 * 1024); // 8 MiB (O0)
    ushort_t* wqkv_b = (ushort_t*)(ws + (size_t)40 * 1024 * 1024); // 1.5 MiB
    ushort_t* wout_b = (ushort_t*)(ws + (size_t)42 * 1024 * 1024); // 0.5 MiB
    float*    Lp     = (float*)   (ws + (size_t)43 * 1024 * 1024); // 0.5 MiB

    k_pre<<<dim3(1024), dim3(256), 0, stream>>>(
        x, g, xnT, wqkv, wout, wqkv_b, wout_b);
    k_gemm<0><<<dim3(B_ * (O3_ / 128) * (N_ / 128)), dim3(256), 0, stream>>>(
        wqkv_b, xnT, qT, kT, vv, nullptr, nullptr);
    k_attn<<<dim3(B_ * H_ * (N_ / 256) * SPLIT), dim3(512), 0, stream>>>(
        qT, kT, vv, attnT, xnT, Lp);
    k_comb<<<dim3(4096), dim3(256), 0, stream>>>(xnT, Lp, attnT);
    k_gemm<1><<<dim3(B_ * (C_ / 128) * (N_ / 128)), dim3(256), 0, stream>>>(
        wout_b, attnT, nullptr, nullptr, nullptr, out, bout);
}

// Round 13
// 92.590 us; speedup vs baseline: 1.1084x; 1.1084x over previous
//
#include <hip/hip_runtime.h>
#include <hip/hip_bf16.h>

// Problem constants
#define B_ 4
#define C_ 512
#define N_ 2048
#define H_ 8
#define D_ 64
#define O3_ 1536   // 3*C
#define SPLIT 2
#define JTN 16     // (N_/64)/SPLIT

typedef __bf16 bf16x8 __attribute__((ext_vector_type(8)));
typedef float f32x4 __attribute__((ext_vector_type(4)));
typedef unsigned short ushort_t;

// q pre-scale: d^-0.5 (=0.125) * log2(e) so softmax uses exp2 directly
#define QSCALE 0.1803368801111137f

__device__ inline ushort_t f2b(float f) {
    __hip_bfloat16 h = __float2bfloat16(f);
    return *reinterpret_cast<ushort_t*>(&h);
}
__device__ inline float b2f(ushort_t u) {
    unsigned v = ((unsigned)u) << 16;
    return *reinterpret_cast<float*>(&v);
}

// async global->LDS DMA, 16B per lane; LDS dest = wave-uniform base + lane*16
__device__ inline void gload16(const ushort_t* g, ushort_t* l) {
    __builtin_amdgcn_global_load_lds(
        (const __attribute__((address_space(1))) unsigned int*)g,
        (__attribute__((address_space(3))) unsigned int*)l, 16, 0, 0);
}

// Session ledger (retired for cause):
//  - setprio around MFMA (R5): -2.2x, lockstep schedule, L2-reuse collapse.
//  - 64-row-wave attn / KV-split-4 (R7/R10): register-footprint-capped at
//    ~2 waves/SIMD; more blocks only queue. 55 vs 46 us.
//  - permlane P-path (R8/R11/R12): correct ONLY under 256-VGPR budget
//    (128-cap miscompiles the "+v" asm pairs); and even passing it is
//    SLOWER than v4 (57 vs 46 us) - serial exp->pack->permlane->MFMA chain
//    vs v4's phase-decoupling LDS bounce.

// ---------------------------------------------------------------------------
// Kernel 1: LN (blocks 0..255) + weight fp32->bf16 convert (blocks 256..1023)
// LN keeps x in registers between the moment pass and the normalize pass.
// ---------------------------------------------------------------------------
__global__ __launch_bounds__(256) void k_pre(const float* __restrict__ x,
                                             const float* __restrict__ g,
                                             ushort_t* __restrict__ xnT,
                                             const float* __restrict__ wqkv,
                                             const float* __restrict__ wout,
                                             ushort_t* __restrict__ wqkv_b,
                                             ushort_t* __restrict__ wout_b) {
    if (blockIdx.x >= 256) {
        int i = (blockIdx.x - 256) * 256 + threadIdx.x;   // 0..196607
        float4 a = reinterpret_cast<const float4*>(wqkv)[i];
        ushort4 o;
        o.x = f2b(a.x); o.y = f2b(a.y); o.z = f2b(a.z); o.w = f2b(a.w);
        reinterpret_cast<ushort4*>(wqkv_b)[i] = o;
        if (i < 65536) {
            float4 c = reinterpret_cast<const float4*>(wout)[i];
            ushort4 oc;
            oc.x = f2b(c.x); oc.y = f2b(c.y); oc.z = f2b(c.z); oc.w = f2b(c.w);
            reinterpret_cast<ushort4*>(wout_b)[i] = oc;
        }
        return;
    }

    int bid = blockIdx.x;
    int b  = bid >> 6;
    int j0 = (bid & 63) * 32;
    int t  = threadIdx.x;

    __shared__ float s_red[8][32];
    __shared__ float s_red2[8][32];
    __shared__ float s_mean[32], s_rstd[32];
    __shared__ float s_g[C_];
    __shared__ __align__(16) ushort_t s_t[32][C_ + 2];

    for (int i = t; i < C_; i += 256) s_g[i] = g[i];

    int jl = t & 31, cg = t >> 5;
    const float* xb = x + (size_t)b * C_ * N_;

    float xv[64];
    float sum = 0.f, sq = 0.f;
#pragma unroll
    for (int i = 0; i < 64; ++i) {
        float v = xb[(size_t)(cg * 64 + i) * N_ + j0 + jl];
        xv[i] = v;
        sum += v; sq += v * v;
    }
    s_red[cg][jl] = sum; s_red2[cg][jl] = sq;
    __syncthreads();
    if (t < 32) {
        float s = 0.f, q = 0.f;
#pragma unroll
        for (int i = 0; i < 8; ++i) { s += s_red[i][t]; q += s_red2[i][t]; }
        float mean = s * (1.0f / C_);
        float var  = q * (1.0f / C_) - mean * mean;
        s_mean[t] = mean;
        s_rstd[t] = rsqrtf(var + 1e-5f);
    }
    __syncthreads();

    float mean = s_mean[jl], rstd = s_rstd[jl];
#pragma unroll
    for (int i = 0; i < 64; ++i) {
        int c = cg * 64 + i;
        s_t[jl][c] = f2b((xv[i] - mean) * rstd * s_g[c]);
    }
    __syncthreads();

    for (int jr = 0; jr < 32; ++jr) {
        unsigned val = *reinterpret_cast<const unsigned*>(&s_t[jr][t * 2]);
        *reinterpret_cast<unsigned*>(
            &xnT[((size_t)(b * N_ + j0 + jr)) * C_ + t * 2]) = val;
    }
}

// ---------------------------------------------------------------------------
// GEMM0 (m97 structure): qkv = w_qkv . xnT  -> qT (scaled) / kT / v
// global_load_lds staging (16B), linear LDS, source-XOR-swizzle + swizzled
// b128 fragment reads. XCD-chunked block swizzle (bijective, grid%8==0).
// ---------------------------------------------------------------------------
__global__ __launch_bounds__(256) void k_gemm0(const ushort_t* __restrict__ A,
                                               const ushort_t* __restrict__ Bt,
                                               ushort_t* __restrict__ qT,
                                               ushort_t* __restrict__ kT,
                                               ushort_t* __restrict__ vv) {
    constexpr int K = C_;
    constexpr int NMT = O3_ / 128;
    constexpr int NWG = B_ * NMT * 16;          // 768; % 8 == 0

    int bid  = blockIdx.x;
    int sbid = (bid & 7) * (NWG / 8) + (bid >> 3);   // XCD-chunked, bijective
    int b    = sbid / (NMT * 16);
    int rem  = sbid % (NMT * 16);
    int mt0  = (rem / 16) * 128;
    int nt0  = (rem % 16) * 128;

    int t = threadIdx.x;
    int w = t >> 6, lane = t & 63;
    int wm = (w >> 1) * 64, wn = (w & 1) * 64;
    int low = lane & 15, hi = lane >> 4;

    __shared__ __align__(16) ushort_t sA[128][64];
    __shared__ __align__(16) ushort_t sB[128][64];

    const ushort_t* Bb = Bt + (size_t)b * N_ * K;

    int srow = lane >> 3;
    int sseg = (lane & 7) ^ srow;
    const ushort_t* Ag = A  + (size_t)(mt0 + w * 32 + srow) * K + sseg * 8;
    const ushort_t* Bg = Bb + (size_t)(nt0 + w * 32 + srow) * K + sseg * 8;

    f32x4 acc[4][4] = {};

    for (int k0 = 0; k0 < K; k0 += 64) {
#pragma unroll
        for (int i = 0; i < 4; ++i) {
            gload16(Ag + (size_t)(i * 8) * K + k0, &sA[w * 32 + i * 8][0]);
            gload16(Bg + (size_t)(i * 8) * K + k0, &sB[w * 32 + i * 8][0]);
        }
        asm volatile("s_waitcnt vmcnt(0)" ::: "memory");
        __syncthreads();
#pragma unroll
        for (int kk = 0; kk < 64; kk += 32) {
            bf16x8 af[4], bfr[4];
#pragma unroll
            for (int mt = 0; mt < 4; ++mt) {
                int cseg = ((kk >> 3) + hi) ^ (low & 7);
                af[mt] = *reinterpret_cast<const bf16x8*>(
                    &sA[wm + mt * 16 + low][cseg * 8]);
            }
#pragma unroll
            for (int nt = 0; nt < 4; ++nt) {
                int cseg = ((kk >> 3) + hi) ^ (low & 7);
                bfr[nt] = *reinterpret_cast<const bf16x8*>(
                    &sB[wn + nt * 16 + low][cseg * 8]);
            }
#pragma unroll
            for (int mt = 0; mt < 4; ++mt)
#pragma unroll
                for (int nt = 0; nt < 4; ++nt)
                    acc[mt][nt] = __builtin_amdgcn_mfma_f32_16x16x32_bf16(
                        af[mt], bfr[nt], acc[mt][nt], 0, 0, 0);
        }
        __syncthreads();
    }

#pragma unroll
    for (int mt = 0; mt < 4; ++mt)
#pragma unroll
        for (int nt = 0; nt < 4; ++nt) {
            int m0 = mt0 + wm + mt * 16 + hi * 4;
            int j  = nt0 + wn + nt * 16 + low;
            if (m0 < 512) {
                ushort4 pk;
                pk.x = f2b(acc[mt][nt][0] * QSCALE);
                pk.y = f2b(acc[mt][nt][1] * QSCALE);
                pk.z = f2b(acc[mt][nt][2] * QSCALE);
                pk.w = f2b(acc[mt][nt][3] * QSCALE);
                *reinterpret_cast<ushort4*>(
                    &qT[(((size_t)(b * H_ + (m0 >> 6)) * N_) + j) * D_ +
                        (m0 & 63)]) = pk;
            } else if (m0 < 1024) {
                int mm = m0 - 512;
                ushort4 pk;
                pk.x = f2b(acc[mt][nt][0]);
                pk.y = f2b(acc[mt][nt][1]);
                pk.z = f2b(acc[mt][nt][2]);
                pk.w = f2b(acc[mt][nt][3]);
                *reinterpret_cast<ushort4*>(
                    &kT[(((size_t)(b * H_ + (mm >> 6)) * N_) + j) * D_ +
                        (mm & 63)]) = pk;
            } else {
                int mm0 = m0 - 1024;
#pragma unroll
                for (int r = 0; r < 4; ++r)
                    vv[(((size_t)(b * H_ + (mm0 >> 6)) * D_) +
                        ((mm0 & 63) + r)) * N_ + j] = f2b(acc[mt][nt][r]);
            }
        }
}

// ---------------------------------------------------------------------------
// Attention v4 (R9 byte-identical, known-good 46us x3 runs): 256-row Q tile,
// 8 waves (512 thr), KV-split 2, LDS-staged dbuf K/V via global_load_lds,
// source-XOR-swizzle + swizzled b128 reads, swapped QK^T -> packed b64 P
// writes, no-max exp2 softmax.
// ---------------------------------------------------------------------------
__global__ __launch_bounds__(512, 4) void k_attn(const ushort_t* __restrict__ qT,
                                                 const ushort_t* __restrict__ kT,
                                                 const ushort_t* __restrict__ vv,
                                                 ushort_t* __restrict__ O0,
                                                 ushort_t* __restrict__ O1,
                                                 float* __restrict__ Lp) {
    int bid  = blockIdx.x;
    int sbid = ((bid & 7) << 6) | (bid >> 3);   // XCD swizzle over 512 blocks
    int it256 = sbid & 7;
    int s     = (sbid >> 3) & 1;
    int h     = (sbid >> 4) & 7;
    int b     = sbid >> 7;
    int i0    = it256 * 256;
    int t = threadIdx.x, w = t >> 6, lane = t & 63;
    int low = lane & 15, hi = lane >> 4;

    __shared__ ushort_t sK[2][64][64];          // linear, seg-swizzled content
    __shared__ ushort_t sV[2][64][64];
    __shared__ __align__(16) ushort_t sPT[256][72];

    const ushort_t* qb = qT + ((size_t)(b * H_ + h)) * N_ * D_;
    const ushort_t* kb = kT + ((size_t)(b * H_ + h)) * N_ * D_;
    const ushort_t* vb = vv + ((size_t)(b * H_ + h)) * D_ * N_;

    int srow = lane >> 3;
    int sseg = (lane & 7) ^ srow;
    const ushort_t* kg = kb + (size_t)(w * 8 + srow) * D_ + sseg * 8;
    const ushort_t* vg = vb + (size_t)(w * 8 + srow) * N_ + sseg * 8;

    // Q fragments: wave w owns q-rows w*32..w*32+31
    bf16x8 qf[2][2];
#pragma unroll
    for (int mt = 0; mt < 2; ++mt)
#pragma unroll
        for (int kx = 0; kx < 2; ++kx)
            qf[mt][kx] = *reinterpret_cast<const bf16x8*>(
                &qb[(size_t)(i0 + w * 32 + mt * 16 + low) * D_ + kx * 32 + hi * 8]);

    // prologue: stage tile 0 into buf 0
    {
        int j0 = s * JTN * 64;
        gload16(kg + (size_t)j0 * D_, &sK[0][w * 8][0]);
        gload16(vg + j0,              &sV[0][w * 8][0]);
    }
    asm volatile("s_waitcnt vmcnt(0)" ::: "memory");
    __syncthreads();

    f32x4 oacc[2][4] = {};
    float lp0 = 0.f, lp1 = 0.f;
    int sw = (low & 7) * 8;   // fragment-read XOR base (shorts)

    int buf = 0;
    for (int jj = 0; jj < JTN; ++jj) {
        int j0c = (s * JTN + jj) * 64;

        // prefetch next tile into the other buffer (async DMA)
        if (jj + 1 < JTN) {
            int j0n = j0c + 64;
            gload16(kg + (size_t)j0n * D_, &sK[buf ^ 1][w * 8][0]);
            gload16(vg + j0n,              &sV[buf ^ 1][w * 8][0]);
        }

        // S^T = K Q^T : rows = keys (64), cols = this wave's 32 q
        f32x4 sacc[2][4] = {};
#pragma unroll
        for (int kx = 0; kx < 2; ++kx) {
            bf16x8 kfx[4];
#pragma unroll
            for (int nt = 0; nt < 4; ++nt)
                kfx[nt] = *reinterpret_cast<const bf16x8*>(
                    &sK[buf][nt * 16 + low][((kx * 4 + hi) * 8) ^ sw]);
#pragma unroll
            for (int mt = 0; mt < 2; ++mt)
#pragma unroll
                for (int nt = 0; nt < 4; ++nt)
                    sacc[mt][nt] = __builtin_amdgcn_mfma_f32_16x16x32_bf16(
                        kfx[nt], qf[mt][kx], sacc[mt][nt], 0, 0, 0);
        }

        // V fragments (LDS reads issued before exp phase; in-order DS pipe)
        bf16x8 vf[2][4];
#pragma unroll
        for (int kx = 0; kx < 2; ++kx)
#pragma unroll
            for (int dt = 0; dt < 4; ++dt)
                vf[kx][dt] = *reinterpret_cast<const bf16x8*>(
                    &sV[buf][dt * 16 + low][((kx * 4 + hi) * 8) ^ sw]);

        // P = exp2(S^T): lane holds keys nt*16+hi*4+r for q-row low(+16mt+32w)
#pragma unroll
        for (int mt = 0; mt < 2; ++mt) {
            int qrow = w * 32 + mt * 16 + low;
#pragma unroll
            for (int nt = 0; nt < 4; ++nt) {
                float p0 = __builtin_amdgcn_exp2f(sacc[mt][nt][0]);
                float p1 = __builtin_amdgcn_exp2f(sacc[mt][nt][1]);
                float p2 = __builtin_amdgcn_exp2f(sacc[mt][nt][2]);
                float p3 = __builtin_amdgcn_exp2f(sacc[mt][nt][3]);
                if (mt == 0) lp0 += (p0 + p1) + (p2 + p3);
                else         lp1 += (p0 + p1) + (p2 + p3);
                ushort4 pk;
                pk.x = f2b(p0); pk.y = f2b(p1); pk.z = f2b(p2); pk.w = f2b(p3);
                *reinterpret_cast<ushort4*>(&sPT[qrow][nt * 16 + hi * 4]) = pk;
            }
        }

        // O += P V
#pragma unroll
        for (int kx = 0; kx < 2; ++kx) {
            bf16x8 ap0 = *reinterpret_cast<const bf16x8*>(
                &sPT[w * 32 + low][kx * 32 + hi * 8]);
            bf16x8 ap1 = *reinterpret_cast<const bf16x8*>(
                &sPT[w * 32 + 16 + low][kx * 32 + hi * 8]);
#pragma unroll
            for (int dt = 0; dt < 4; ++dt) {
                oacc[0][dt] = __builtin_amdgcn_mfma_f32_16x16x32_bf16(
                    ap0, vf[kx][dt], oacc[0][dt], 0, 0, 0);
                oacc[1][dt] = __builtin_amdgcn_mfma_f32_16x16x32_bf16(
                    ap1, vf[kx][dt], oacc[1][dt], 0, 0, 0);
            }
        }

        // own prefetch DMA landed (issued a full compute phase ago), then sync
        asm volatile("s_waitcnt vmcnt(0)" ::: "memory");
        __syncthreads();
        buf ^= 1;
    }

    // reduce row-sum partials across the 4 hi-groups
    lp0 += __shfl_xor(lp0, 16); lp0 += __shfl_xor(lp0, 32);
    lp1 += __shfl_xor(lp1, 16); lp1 += __shfl_xor(lp1, 32);

    float* lrow = Lp + ((size_t)((s * B_ + b) * H_ + h)) * N_ + i0 + w * 32;
    if (lane < 16) {
        lrow[low]      = lp0;
        lrow[16 + low] = lp1;
    }

    // partial O (unnormalized) in attnT layout [b][i][h*64+d], bf16
    ushort_t* op = (s == 0 ? O0 : O1) +
                   ((size_t)(b * N_ + i0 + w * 32)) * C_ + h * D_;
#pragma unroll
    for (int mt = 0; mt < 2; ++mt)
#pragma unroll
        for (int dt = 0; dt < 4; ++dt)
#pragma unroll
            for (int r = 0; r < 4; ++r)
                op[(size_t)(mt * 16 + hi * 4 + r) * C_ + dt * 16 + low] =
                    f2b(oacc[mt][dt][r]);
}

// ---------------------------------------------------------------------------
// GEMM1 with fused combine: out = w_out . [(O0+O1)/l] + b_out
// Tile 64(M) x 128(N), grid 512 (2 blocks/CU; old 128x128 was 1/CU,
// latency-bound). A (weights) via DMA; B reg-staged with the combine math
// inline: each staged 64-col k-chunk is one head (h = k0/64), so the
// divisor l(b,h,j) is row-uniform per chunk. Same XOR content pre-swizzle
// as the DMA path: load global colseg (lane&7)^srow, write LDS colseg
// (lane&7). Eliminates the separate k_comb dispatch + attnT HBM round-trip.
// ---------------------------------------------------------------------------
__global__ __launch_bounds__(256) void k_gemm1(const ushort_t* __restrict__ A,
                                               const ushort_t* __restrict__ O0,
                                               const ushort_t* __restrict__ O1,
                                               const float* __restrict__ Lp,
                                               float* __restrict__ out,
                                               const float* __restrict__ b_out) {
    constexpr int K = C_;
    constexpr int NMT = C_ / 64;                // 8
    constexpr int NWG = B_ * NMT * 16;          // 512; % 8 == 0

    int bid  = blockIdx.x;
    int sbid = (bid & 7) * (NWG / 8) + (bid >> 3);   // XCD-chunked, bijective
    int b    = sbid / (NMT * 16);
    int rem  = sbid % (NMT * 16);
    int mt0  = (rem / 16) * 64;
    int nt0  = (rem % 16) * 128;

    int t = threadIdx.x;
    int w = t >> 6, lane = t & 63;
    int wm = (w >> 1) * 32, wn = (w & 1) * 64;
    int low = lane & 15, hi = lane >> 4;

    __shared__ __align__(16) ushort_t sA[64][64];
    __shared__ __align__(16) ushort_t sB[128][64];

    int srow = lane >> 3;                        // 0..7
    int sseg = (lane & 7) ^ srow;                // global colseg to fetch
    int wseg = lane & 7;                         // LDS colseg to write
    const ushort_t* Ag = A + (size_t)(mt0 + w * 16 + srow) * K + sseg * 8;

    f32x4 acc[2][4] = {};

    for (int k0 = 0; k0 < K; k0 += 64) {
        int h = k0 >> 6;                         // 64-col chunk == one head
        // A: DMA 2x8 rows per wave
#pragma unroll
        for (int i = 0; i < 2; ++i)
            gload16(Ag + (size_t)(i * 8) * K + k0, &sA[w * 16 + i * 8][0]);

        // B: reg-staged with fused combine; wave w stages rows w*32..+31
#pragma unroll
        for (int it = 0; it < 4; ++it) {
            int jr = w * 32 + it * 8 + srow;     // block-local row
            int j  = nt0 + jr;                   // token index
            size_t obase = ((size_t)(b * N_ + j)) * C_ + k0 + sseg * 8;
            ushort4 a0 = *reinterpret_cast<const ushort4*>(&O0[obase]);
            ushort4 a1 = *reinterpret_cast<const ushort4*>(&O0[obase + 4]);
            ushort4 c0 = *reinterpret_cast<const ushort4*>(&O1[obase]);
            ushort4 c1 = *reinterpret_cast<const ushort4*>(&O1[obase + 4]);
            float l = Lp[((size_t)(b * H_ + h)) * N_ + j] +
                      Lp[((size_t)((B_ + b) * H_ + h)) * N_ + j];
            float linv = 1.0f / l;
            ushort4 o0, o1;
            o0.x = f2b((b2f(a0.x) + b2f(c0.x)) * linv);
            o0.y = f2b((b2f(a0.y) + b2f(c0.y)) * linv);
            o0.z = f2b((b2f(a0.z) + b2f(c0.z)) * linv);
            o0.w = f2b((b2f(a0.w) + b2f(c0.w)) * linv);
            o1.x = f2b((b2f(a1.x) + b2f(c1.x)) * linv);
            o1.y = f2b((b2f(a1.y) + b2f(c1.y)) * linv);
            o1.z = f2b((b2f(a1.z) + b2f(c1.z)) * linv);
            o1.w = f2b((b2f(a1.w) + b2f(c1.w)) * linv);
            *reinterpret_cast<ushort4*>(&sB[jr][wseg * 8])     = o0;
            *reinterpret_cast<ushort4*>(&sB[jr][wseg * 8 + 4]) = o1;
        }

        asm volatile("s_waitcnt vmcnt(0)" ::: "memory");
        __syncthreads();
#pragma unroll
        for (int kk = 0; kk < 64; kk += 32) {
            bf16x8 af[2], bfr[4];
#pragma unroll
            for (int mt = 0; mt < 2; ++mt) {
                int cseg = ((kk >> 3) + hi) ^ (low & 7);
                af[mt] = *reinterpret_cast<const bf16x8*>(
                    &sA[wm + mt * 16 + low][cseg * 8]);
            }
#pragma unroll
            for (int nt = 0; nt < 4; ++nt) {
                int cseg = ((kk >> 3) + hi) ^ (low & 7);
                bfr[nt] = *reinterpret_cast<const bf16x8*>(
                    &sB[wn + nt * 16 + low][cseg * 8]);
            }
#pragma unroll
            for (int mt = 0; mt < 2; ++mt)
#pragma unroll
                for (int nt = 0; nt < 4; ++nt)
                    acc[mt][nt] = __builtin_amdgcn_mfma_f32_16x16x32_bf16(
                        af[mt], bfr[nt], acc[mt][nt], 0, 0, 0);
        }
        __syncthreads();
    }

#pragma unroll
    for (int mt = 0; mt < 2; ++mt)
#pragma unroll
        for (int nt = 0; nt < 4; ++nt) {
            int m0 = mt0 + wm + mt * 16 + hi * 4;
            int j  = nt0 + wn + nt * 16 + low;
#pragma unroll
            for (int r = 0; r < 4; ++r)
                out[((size_t)(b * C_ + m0 + r)) * N_ + j] =
                    acc[mt][nt][r] + b_out[m0 + r];
        }
}

// ---------------------------------------------------------------------------
// Launch
// ---------------------------------------------------------------------------
extern "C" void kernel_launch(void* const* d_in, const int* in_sizes, int n_in,
                              void* d_out, int out_size, void* d_ws, size_t ws_size,
                              hipStream_t stream) {
    const float* x    = (const float*)d_in[0];
    const float* g    = (const float*)d_in[1];
    const float* wqkv = (const float*)d_in[2];
    const float* wout = (const float*)d_in[3];
    const float* bout = (const float*)d_in[4];
    float* out = (float*)d_out;

    char* ws = (char*)d_ws;
    ushort_t* xnT    = (ushort_t*)(ws);                            // 8 MiB (O1)
    ushort_t* qT     = (ushort_t*)(ws + (size_t)8  * 1024 * 1024); // 8 MiB
    ushort_t* kT     = (ushort_t*)(ws + (size_t)16 * 1024 * 1024); // 8 MiB
    ushort_t* vv     = (ushort_t*)(ws + (size_t)24 * 1024 * 1024); // 8 MiB
    ushort_t* O0     = (ushort_t*)(ws + (size_t)32 * 1024 * 1024); // 8 MiB
    ushort_t* wqkv_b = (ushort_t*)(ws + (size_t)40 * 1024 * 1024); // 1.5 MiB
    ushort_t* wout_b = (ushort_t*)(ws + (size_t)42 * 1024 * 1024); // 0.5 MiB
    float*    Lp     = (float*)   (ws + (size_t)43 * 1024 * 1024); // 0.5 MiB

    k_pre<<<dim3(1024), dim3(256), 0, stream>>>(
        x, g, xnT, wqkv, wout, wqkv_b, wout_b);
    k_gemm0<<<dim3(B_ * (O3_ / 128) * (N_ / 128)), dim3(256), 0, stream>>>(
        wqkv_b, xnT, qT, kT, vv);
    k_attn<<<dim3(B_ * H_ * (N_ / 256) * SPLIT), dim3(512), 0, stream>>>(
        qT, kT, vv, O0, xnT, Lp);
    k_gemm1<<<dim3(B_ * (C_ / 64) * (N_ / 128)), dim3(256), 0, stream>>>(
        wout_b, O0, xnT, Lp, out, bout);
}

// Round 14
// 92.551 us; speedup vs baseline: 1.1089x; 1.0004x over previous
//
#include <hip/hip_runtime.h>
#include <hip/hip_bf16.h>

// Problem constants
#define B_ 4
#define C_ 512
#define N_ 2048
#define H_ 8
#define D_ 64
#define O3_ 1536   // 3*C
#define SPLIT 2
#define JTN 16     // (N_/64)/SPLIT

typedef __bf16 bf16x8 __attribute__((ext_vector_type(8)));
typedef float f32x4 __attribute__((ext_vector_type(4)));
typedef unsigned short ushort_t;

// q pre-scale: d^-0.5 (=0.125) * log2(e) so softmax uses exp2 directly
#define QSCALE 0.1803368801111137f

__device__ inline ushort_t f2b(float f) {
    __hip_bfloat16 h = __float2bfloat16(f);
    return *reinterpret_cast<ushort_t*>(&h);
}
__device__ inline float b2f(ushort_t u) {
    unsigned v = ((unsigned)u) << 16;
    return *reinterpret_cast<float*>(&v);
}

// async global->LDS DMA, 16B per lane; LDS dest = wave-uniform base + lane*16
__device__ inline void gload16(const ushort_t* g, ushort_t* l) {
    __builtin_amdgcn_global_load_lds(
        (const __attribute__((address_space(1))) unsigned int*)g,
        (__attribute__((address_space(3))) unsigned int*)l, 16, 0, 0);
}

// Session ledger (retired for cause):
//  - setprio around MFMA (R5): -2.2x, lockstep schedule, L2-reuse collapse.
//  - 64-row-wave attn / KV-split-4 (R7/R10): register-footprint-capped at
//    ~2 waves/SIMD; more blocks only queue. 55 vs 46 us.
//  - permlane P-path (R8/R11/R12): correct ONLY under 256-VGPR budget
//    (128-cap miscompiles the "+v" asm pairs); and even passing it is
//    SLOWER than v4 (57 vs 46 us) - serial exp->pack->permlane->MFMA chain
//    vs v4's phase-decoupling LDS bounce.
//  - combine fused into gemm1 B-staging (R13): net 0 - the per-row combine
//    VALU (~400 ops/thread/k-step) on gemm1's critical path eats the saved
//    k_comb dispatch. Kept (no loss, one fewer buffer), not a win.

// ---------------------------------------------------------------------------
// Kernel 1: LN (blocks 0..255) + weight fp32->bf16 convert (blocks 256..1023)
// LN keeps x in registers between the moment pass and the normalize pass.
// ---------------------------------------------------------------------------
__global__ __launch_bounds__(256) void k_pre(const float* __restrict__ x,
                                             const float* __restrict__ g,
                                             ushort_t* __restrict__ xnT,
                                             const float* __restrict__ wqkv,
                                             const float* __restrict__ wout,
                                             ushort_t* __restrict__ wqkv_b,
                                             ushort_t* __restrict__ wout_b) {
    if (blockIdx.x >= 256) {
        int i = (blockIdx.x - 256) * 256 + threadIdx.x;   // 0..196607
        float4 a = reinterpret_cast<const float4*>(wqkv)[i];
        ushort4 o;
        o.x = f2b(a.x); o.y = f2b(a.y); o.z = f2b(a.z); o.w = f2b(a.w);
        reinterpret_cast<ushort4*>(wqkv_b)[i] = o;
        if (i < 65536) {
            float4 c = reinterpret_cast<const float4*>(wout)[i];
            ushort4 oc;
            oc.x = f2b(c.x); oc.y = f2b(c.y); oc.z = f2b(c.z); oc.w = f2b(c.w);
            reinterpret_cast<ushort4*>(wout_b)[i] = oc;
        }
        return;
    }

    int bid = blockIdx.x;
    int b  = bid >> 6;
    int j0 = (bid & 63) * 32;
    int t  = threadIdx.x;

    __shared__ float s_red[8][32];
    __shared__ float s_red2[8][32];
    __shared__ float s_mean[32], s_rstd[32];
    __shared__ float s_g[C_];
    __shared__ __align__(16) ushort_t s_t[32][C_ + 2];

    for (int i = t; i < C_; i += 256) s_g[i] = g[i];

    int jl = t & 31, cg = t >> 5;
    const float* xb = x + (size_t)b * C_ * N_;

    float xv[64];
    float sum = 0.f, sq = 0.f;
#pragma unroll
    for (int i = 0; i < 64; ++i) {
        float v = xb[(size_t)(cg * 64 + i) * N_ + j0 + jl];
        xv[i] = v;
        sum += v; sq += v * v;
    }
    s_red[cg][jl] = sum; s_red2[cg][jl] = sq;
    __syncthreads();
    if (t < 32) {
        float s = 0.f, q = 0.f;
#pragma unroll
        for (int i = 0; i < 8; ++i) { s += s_red[i][t]; q += s_red2[i][t]; }
        float mean = s * (1.0f / C_);
        float var  = q * (1.0f / C_) - mean * mean;
        s_mean[t] = mean;
        s_rstd[t] = rsqrtf(var + 1e-5f);
    }
    __syncthreads();

    float mean = s_mean[jl], rstd = s_rstd[jl];
#pragma unroll
    for (int i = 0; i < 64; ++i) {
        int c = cg * 64 + i;
        s_t[jl][c] = f2b((xv[i] - mean) * rstd * s_g[c]);
    }
    __syncthreads();

    for (int jr = 0; jr < 32; ++jr) {
        unsigned val = *reinterpret_cast<const unsigned*>(&s_t[jr][t * 2]);
        *reinterpret_cast<unsigned*>(
            &xnT[((size_t)(b * N_ + j0 + jr)) * C_ + t * 2]) = val;
    }
}

// ---------------------------------------------------------------------------
// GEMM0 (m97 structure): qkv = w_qkv . xnT  -> qT (scaled) / kT / v
// global_load_lds staging (16B), linear LDS, source-XOR-swizzle + swizzled
// b128 fragment reads. XCD-chunked block swizzle (bijective, grid%8==0).
// ---------------------------------------------------------------------------
__global__ __launch_bounds__(256) void k_gemm0(const ushort_t* __restrict__ A,
                                               const ushort_t* __restrict__ Bt,
                                               ushort_t* __restrict__ qT,
                                               ushort_t* __restrict__ kT,
                                               ushort_t* __restrict__ vv) {
    constexpr int K = C_;
    constexpr int NMT = O3_ / 128;
    constexpr int NWG = B_ * NMT * 16;          // 768; % 8 == 0

    int bid  = blockIdx.x;
    int sbid = (bid & 7) * (NWG / 8) + (bid >> 3);   // XCD-chunked, bijective
    int b    = sbid / (NMT * 16);
    int rem  = sbid % (NMT * 16);
    int mt0  = (rem / 16) * 128;
    int nt0  = (rem % 16) * 128;

    int t = threadIdx.x;
    int w = t >> 6, lane = t & 63;
    int wm = (w >> 1) * 64, wn = (w & 1) * 64;
    int low = lane & 15, hi = lane >> 4;

    __shared__ __align__(16) ushort_t sA[128][64];
    __shared__ __align__(16) ushort_t sB[128][64];

    const ushort_t* Bb = Bt + (size_t)b * N_ * K;

    int srow = lane >> 3;
    int sseg = (lane & 7) ^ srow;
    const ushort_t* Ag = A  + (size_t)(mt0 + w * 32 + srow) * K + sseg * 8;
    const ushort_t* Bg = Bb + (size_t)(nt0 + w * 32 + srow) * K + sseg * 8;

    f32x4 acc[4][4] = {};

    for (int k0 = 0; k0 < K; k0 += 64) {
#pragma unroll
        for (int i = 0; i < 4; ++i) {
            gload16(Ag + (size_t)(i * 8) * K + k0, &sA[w * 32 + i * 8][0]);
            gload16(Bg + (size_t)(i * 8) * K + k0, &sB[w * 32 + i * 8][0]);
        }
        asm volatile("s_waitcnt vmcnt(0)" ::: "memory");
        __syncthreads();
#pragma unroll
        for (int kk = 0; kk < 64; kk += 32) {
            bf16x8 af[4], bfr[4];
#pragma unroll
            for (int mt = 0; mt < 4; ++mt) {
                int cseg = ((kk >> 3) + hi) ^ (low & 7);
                af[mt] = *reinterpret_cast<const bf16x8*>(
                    &sA[wm + mt * 16 + low][cseg * 8]);
            }
#pragma unroll
            for (int nt = 0; nt < 4; ++nt) {
                int cseg = ((kk >> 3) + hi) ^ (low & 7);
                bfr[nt] = *reinterpret_cast<const bf16x8*>(
                    &sB[wn + nt * 16 + low][cseg * 8]);
            }
#pragma unroll
            for (int mt = 0; mt < 4; ++mt)
#pragma unroll
                for (int nt = 0; nt < 4; ++nt)
                    acc[mt][nt] = __builtin_amdgcn_mfma_f32_16x16x32_bf16(
                        af[mt], bfr[nt], acc[mt][nt], 0, 0, 0);
        }
        __syncthreads();
    }

#pragma unroll
    for (int mt = 0; mt < 4; ++mt)
#pragma unroll
        for (int nt = 0; nt < 4; ++nt) {
            int m0 = mt0 + wm + mt * 16 + hi * 4;
            int j  = nt0 + wn + nt * 16 + low;
            if (m0 < 512) {
                ushort4 pk;
                pk.x = f2b(acc[mt][nt][0] * QSCALE);
                pk.y = f2b(acc[mt][nt][1] * QSCALE);
                pk.z = f2b(acc[mt][nt][2] * QSCALE);
                pk.w = f2b(acc[mt][nt][3] * QSCALE);
                *reinterpret_cast<ushort4*>(
                    &qT[(((size_t)(b * H_ + (m0 >> 6)) * N_) + j) * D_ +
                        (m0 & 63)]) = pk;
            } else if (m0 < 1024) {
                int mm = m0 - 512;
                ushort4 pk;
                pk.x = f2b(acc[mt][nt][0]);
                pk.y = f2b(acc[mt][nt][1]);
                pk.z = f2b(acc[mt][nt][2]);
                pk.w = f2b(acc[mt][nt][3]);
                *reinterpret_cast<ushort4*>(
                    &kT[(((size_t)(b * H_ + (mm >> 6)) * N_) + j) * D_ +
                        (mm & 63)]) = pk;
            } else {
                int mm0 = m0 - 1024;
#pragma unroll
                for (int r = 0; r < 4; ++r)
                    vv[(((size_t)(b * H_ + (mm0 >> 6)) * D_) +
                        ((mm0 & 63) + r)) * N_ + j] = f2b(acc[mt][nt][r]);
            }
        }
}

// ---------------------------------------------------------------------------
// Attention v9: v4 geometry (8 waves x 32 q-rows, 256-row tile, KV-split 2)
// + T4 counted-vmcnt triple-buffer: prefetch distance 2, wait vmcnt(2) --
// never drain DMA to 0 in the main loop. LDS budget held at 69632 B
// (2 blocks/CU) by halving sPT to [256][40]: PV runs in two 32-key halves
// (exp nt{0,1} -> P write -> PV kx=0 -> exp nt{2,3} -> PV kx=1). Wave-private
// sPT rows + in-order DS pipe make the column reuse hazard-free.
// ---------------------------------------------------------------------------
__global__ __launch_bounds__(512, 4) void k_attn(const ushort_t* __restrict__ qT,
                                                 const ushort_t* __restrict__ kT,
                                                 const ushort_t* __restrict__ vv,
                                                 ushort_t* __restrict__ O0,
                                                 ushort_t* __restrict__ O1,
                                                 float* __restrict__ Lp) {
    int bid  = blockIdx.x;
    int sbid = ((bid & 7) << 6) | (bid >> 3);   // XCD swizzle over 512 blocks
    int it256 = sbid & 7;
    int s     = (sbid >> 3) & 1;
    int h     = (sbid >> 4) & 7;
    int b     = sbid >> 7;
    int i0    = it256 * 256;
    int t = threadIdx.x, w = t >> 6, lane = t & 63;
    int low = lane & 15, hi = lane >> 4;

    __shared__ ushort_t sK[3][64][64];          // linear, seg-swizzled content
    __shared__ ushort_t sV[3][64][64];
    __shared__ __align__(16) ushort_t sPT[256][40];   // 32-key half + 8 pad

    const ushort_t* qb = qT + ((size_t)(b * H_ + h)) * N_ * D_;
    const ushort_t* kb = kT + ((size_t)(b * H_ + h)) * N_ * D_;
    const ushort_t* vb = vv + ((size_t)(b * H_ + h)) * D_ * N_;

    int srow = lane >> 3;
    int sseg = (lane & 7) ^ srow;
    const ushort_t* kg = kb + (size_t)(w * 8 + srow) * D_ + sseg * 8;
    const ushort_t* vg = vb + (size_t)(w * 8 + srow) * N_ + sseg * 8;

    // Q fragments: wave w owns q-rows w*32..w*32+31
    bf16x8 qf[2][2];
#pragma unroll
    for (int mt = 0; mt < 2; ++mt)
#pragma unroll
        for (int kx = 0; kx < 2; ++kx)
            qf[mt][kx] = *reinterpret_cast<const bf16x8*>(
                &qb[(size_t)(i0 + w * 32 + mt * 16 + low) * D_ + kx * 32 + hi * 8]);

    // prologue: stage jt=0 -> buf0 and jt=1 -> buf1; wait only for buf0
    {
        int j0 = s * JTN * 64;
        gload16(kg + (size_t)j0 * D_,        &sK[0][w * 8][0]);
        gload16(vg + j0,                     &sV[0][w * 8][0]);
        gload16(kg + (size_t)(j0 + 64) * D_, &sK[1][w * 8][0]);
        gload16(vg + (j0 + 64),              &sV[1][w * 8][0]);
    }
    asm volatile("s_waitcnt vmcnt(2)" ::: "memory");
    __syncthreads();

    f32x4 oacc[2][4] = {};
    float lp0 = 0.f, lp1 = 0.f;
    int sw = (low & 7) * 8;   // fragment-read XOR base (shorts)

    int bcur = 0;
    for (int jj = 0; jj < JTN; ++jj) {
        // prefetch tile jj+2 into the third buffer (async DMA, depth 2)
        int bnext = bcur + 2; if (bnext >= 3) bnext -= 3;
        bool pf = (jj + 2 < JTN);
        if (pf) {
            int j0n = (s * JTN + jj + 2) * 64;
            gload16(kg + (size_t)j0n * D_, &sK[bnext][w * 8][0]);
            gload16(vg + j0n,              &sV[bnext][w * 8][0]);
        }

        // S^T = K Q^T : rows = keys (64), cols = this wave's 32 q
        f32x4 sacc[2][4] = {};
#pragma unroll
        for (int kx = 0; kx < 2; ++kx) {
            bf16x8 kfx[4];
#pragma unroll
            for (int nt = 0; nt < 4; ++nt)
                kfx[nt] = *reinterpret_cast<const bf16x8*>(
                    &sK[bcur][nt * 16 + low][((kx * 4 + hi) * 8) ^ sw]);
#pragma unroll
            for (int mt = 0; mt < 2; ++mt)
#pragma unroll
                for (int nt = 0; nt < 4; ++nt)
                    sacc[mt][nt] = __builtin_amdgcn_mfma_f32_16x16x32_bf16(
                        kfx[nt], qf[mt][kx], sacc[mt][nt], 0, 0, 0);
        }

        // V fragments (LDS reads issued before exp phase; in-order DS pipe)
        bf16x8 vf[2][4];
#pragma unroll
        for (int kx = 0; kx < 2; ++kx)
#pragma unroll
            for (int dt = 0; dt < 4; ++dt)
                vf[kx][dt] = *reinterpret_cast<const bf16x8*>(
                    &sV[bcur][dt * 16 + low][((kx * 4 + hi) * 8) ^ sw]);

        // two 32-key halves: exp2 + P write (32 cols), then PV for that half.
        // WAR on sPT cols is safe: same-wave DS ops execute in program order.
#pragma unroll
        for (int hx = 0; hx < 2; ++hx) {
#pragma unroll
            for (int mt = 0; mt < 2; ++mt) {
                int qrow = w * 32 + mt * 16 + low;
#pragma unroll
                for (int nt2 = 0; nt2 < 2; ++nt2) {
                    int nt = hx * 2 + nt2;
                    float p0 = __builtin_amdgcn_exp2f(sacc[mt][nt][0]);
                    float p1 = __builtin_amdgcn_exp2f(sacc[mt][nt][1]);
                    float p2 = __builtin_amdgcn_exp2f(sacc[mt][nt][2]);
                    float p3 = __builtin_amdgcn_exp2f(sacc[mt][nt][3]);
                    if (mt == 0) lp0 += (p0 + p1) + (p2 + p3);
                    else         lp1 += (p0 + p1) + (p2 + p3);
                    ushort4 pk;
                    pk.x = f2b(p0); pk.y = f2b(p1);
                    pk.z = f2b(p2); pk.w = f2b(p3);
                    *reinterpret_cast<ushort4*>(
                        &sPT[qrow][nt2 * 16 + hi * 4]) = pk;
                }
            }
            bf16x8 ap0 = *reinterpret_cast<const bf16x8*>(
                &sPT[w * 32 + low][hi * 8]);
            bf16x8 ap1 = *reinterpret_cast<const bf16x8*>(
                &sPT[w * 32 + 16 + low][hi * 8]);
#pragma unroll
            for (int dt = 0; dt < 4; ++dt) {
                oacc[0][dt] = __builtin_amdgcn_mfma_f32_16x16x32_bf16(
                    ap0, vf[hx][dt], oacc[0][dt], 0, 0, 0);
                oacc[1][dt] = __builtin_amdgcn_mfma_f32_16x16x32_bf16(
                    ap1, vf[hx][dt], oacc[1][dt], 0, 0, 0);
            }
        }

        // counted wait: keep tile jj+2's loads in flight; only require
        // tile jj+1 (issued two iterations of compute ago) to have landed.
        if (pf) asm volatile("s_waitcnt vmcnt(2)" ::: "memory");
        else    asm volatile("s_waitcnt vmcnt(0)" ::: "memory");
        __syncthreads();
        bcur += 1; if (bcur >= 3) bcur -= 3;
    }

    // reduce row-sum partials across the 4 hi-groups
    lp0 += __shfl_xor(lp0, 16); lp0 += __shfl_xor(lp0, 32);
    lp1 += __shfl_xor(lp1, 16); lp1 += __shfl_xor(lp1, 32);

    float* lrow = Lp + ((size_t)((s * B_ + b) * H_ + h)) * N_ + i0 + w * 32;
    if (lane < 16) {
        lrow[low]      = lp0;
        lrow[16 + low] = lp1;
    }

    // partial O (unnormalized) in attnT layout [b][i][h*64+d], bf16
    ushort_t* op = (s == 0 ? O0 : O1) +
                   ((size_t)(b * N_ + i0 + w * 32)) * C_ + h * D_;
#pragma unroll
    for (int mt = 0; mt < 2; ++mt)
#pragma unroll
        for (int dt = 0; dt < 4; ++dt)
#pragma unroll
            for (int r = 0; r < 4; ++r)
                op[(size_t)(mt * 16 + hi * 4 + r) * C_ + dt * 16 + low] =
                    f2b(oacc[mt][dt][r]);
}

// ---------------------------------------------------------------------------
// GEMM1 with fused combine: out = w_out . [(O0+O1)/l] + b_out
// Tile 64(M) x 128(N), grid 512. A (weights) via DMA; B reg-staged with the
// combine math inline (divisor row-uniform per 64-col head chunk).
// ---------------------------------------------------------------------------
__global__ __launch_bounds__(256) void k_gemm1(const ushort_t* __restrict__ A,
                                               const ushort_t* __restrict__ O0,
                                               const ushort_t* __restrict__ O1,
                                               const float* __restrict__ Lp,
                                               float* __restrict__ out,
                                               const float* __restrict__ b_out) {
    constexpr int K = C_;
    constexpr int NMT = C_ / 64;                // 8
    constexpr int NWG = B_ * NMT * 16;          // 512; % 8 == 0

    int bid  = blockIdx.x;
    int sbid = (bid & 7) * (NWG / 8) + (bid >> 3);   // XCD-chunked, bijective
    int b    = sbid / (NMT * 16);
    int rem  = sbid % (NMT * 16);
    int mt0  = (rem / 16) * 64;
    int nt0  = (rem % 16) * 128;

    int t = threadIdx.x;
    int w = t >> 6, lane = t & 63;
    int wm = (w >> 1) * 32, wn = (w & 1) * 64;
    int low = lane & 15, hi = lane >> 4;

    __shared__ __align__(16) ushort_t sA[64][64];
    __shared__ __align__(16) ushort_t sB[128][64];

    int srow = lane >> 3;                        // 0..7
    int sseg = (lane & 7) ^ srow;                // global colseg to fetch
    int wseg = lane & 7;                         // LDS colseg to write
    const ushort_t* Ag = A + (size_t)(mt0 + w * 16 + srow) * K + sseg * 8;

    f32x4 acc[2][4] = {};

    for (int k0 = 0; k0 < K; k0 += 64) {
        int h = k0 >> 6;                         // 64-col chunk == one head
        // A: DMA 2x8 rows per wave
#pragma unroll
        for (int i = 0; i < 2; ++i)
            gload16(Ag + (size_t)(i * 8) * K + k0, &sA[w * 16 + i * 8][0]);

        // B: reg-staged with fused combine; wave w stages rows w*32..+31
#pragma unroll
        for (int it = 0; it < 4; ++it) {
            int jr = w * 32 + it * 8 + srow;     // block-local row
            int j  = nt0 + jr;                   // token index
            size_t obase = ((size_t)(b * N_ + j)) * C_ + k0 + sseg * 8;
            ushort4 a0 = *reinterpret_cast<const ushort4*>(&O0[obase]);
            ushort4 a1 = *reinterpret_cast<const ushort4*>(&O0[obase + 4]);
            ushort4 c0 = *reinterpret_cast<const ushort4*>(&O1[obase]);
            ushort4 c1 = *reinterpret_cast<const ushort4*>(&O1[obase + 4]);
            float l = Lp[((size_t)(b * H_ + h)) * N_ + j] +
                      Lp[((size_t)((B_ + b) * H_ + h)) * N_ + j];
            float linv = 1.0f / l;
            ushort4 o0, o1;
            o0.x = f2b((b2f(a0.x) + b2f(c0.x)) * linv);
            o0.y = f2b((b2f(a0.y) + b2f(c0.y)) * linv);
            o0.z = f2b((b2f(a0.z) + b2f(c0.z)) * linv);
            o0.w = f2b((b2f(a0.w) + b2f(c0.w)) * linv);
            o1.x = f2b((b2f(a1.x) + b2f(c1.x)) * linv);
            o1.y = f2b((b2f(a1.y) + b2f(c1.y)) * linv);
            o1.z = f2b((b2f(a1.z) + b2f(c1.z)) * linv);
            o1.w = f2b((b2f(a1.w) + b2f(c1.w)) * linv);
            *reinterpret_cast<ushort4*>(&sB[jr][wseg * 8])     = o0;
            *reinterpret_cast<ushort4*>(&sB[jr][wseg * 8 + 4]) = o1;
        }

        asm volatile("s_waitcnt vmcnt(0)" ::: "memory");
        __syncthreads();
#pragma unroll
        for (int kk = 0; kk < 64; kk += 32) {
            bf16x8 af[2], bfr[4];
#pragma unroll
            for (int mt = 0; mt < 2; ++mt) {
                int cseg = ((kk >> 3) + hi) ^ (low & 7);
                af[mt] = *reinterpret_cast<const bf16x8*>(
                    &sA[wm + mt * 16 + low][cseg * 8]);
            }
#pragma unroll
            for (int nt = 0; nt < 4; ++nt) {
                int cseg = ((kk >> 3) + hi) ^ (low & 7);
                bfr[nt] = *reinterpret_cast<const bf16x8*>(
                    &sB[wn + nt * 16 + low][cseg * 8]);
            }
#pragma unroll
            for (int mt = 0; mt < 2; ++mt)
#pragma unroll
                for (int nt = 0; nt < 4; ++nt)
                    acc[mt][nt] = __builtin_amdgcn_mfma_f32_16x16x32_bf16(
                        af[mt], bfr[nt], acc[mt][nt], 0, 0, 0);
        }
        __syncthreads();
    }

#pragma unroll
    for (int mt = 0; mt < 2; ++mt)
#pragma unroll
        for (int nt = 0; nt < 4; ++nt) {
            int m0 = mt0 + wm + mt * 16 + hi * 4;
            int j  = nt0 + wn + nt * 16 + low;
#pragma unroll
            for (int r = 0; r < 4; ++r)
                out[((size_t)(b * C_ + m0 + r)) * N_ + j] =
                    acc[mt][nt][r] + b_out[m0 + r];
        }
}

// ---------------------------------------------------------------------------
// Launch
// ---------------------------------------------------------------------------
extern "C" void kernel_launch(void* const* d_in, const int* in_sizes, int n_in,
                              void* d_out, int out_size, void* d_ws, size_t ws_size,
                              hipStream_t stream) {
    const float* x    = (const float*)d_in[0];
    const float* g    = (const float*)d_in[1];
    const float* wqkv = (const float*)d_in[2];
    const float* wout = (const float*)d_in[3];
    const float* bout = (const float*)d_in[4];
    float* out = (float*)d_out;

    char* ws = (char*)d_ws;
    ushort_t* xnT    = (ushort_t*)(ws);                            // 8 MiB (O1)
    ushort_t* qT     = (ushort_t*)(ws + (size_t)8  * 1024 * 1024); // 8 MiB
    ushort_t* kT     = (ushort_t*)(ws + (size_t)16 * 1024 * 1024); // 8 MiB
    ushort_t* vv     = (ushort_t*)(ws + (size_t)24 * 1024 * 1024); // 8 MiB
    ushort_t* O0     = (ushort_t*)(ws + (size_t)32 * 1024 * 1024); // 8 MiB
    ushort_t* wqkv_b = (ushort_t*)(ws + (size_t)40 * 1024 * 1024); // 1.5 MiB
    ushort_t* wout_b = (ushort_t*)(ws + (size_t)42 * 1024 * 1024); // 0.5 MiB
    float*    Lp     = (float*)   (ws + (size_t)43 * 1024 * 1024); // 0.5 MiB

    k_pre<<<dim3(1024), dim3(256), 0, stream>>>(
        x, g, xnT, wqkv, wout, wqkv_b, wout_b);
    k_gemm0<<<dim3(B_ * (O3_ / 128) * (N_ / 128)), dim3(256), 0, stream>>>(
        wqkv_b, xnT, qT, kT, vv);
    k_attn<<<dim3(B_ * H_ * (N_ / 256) * SPLIT), dim3(512), 0, stream>>>(
        qT, kT, vv, O0, xnT, Lp);
    k_gemm1<<<dim3(B_ * (C_ / 64) * (N_ / 128)), dim3(256), 0, stream>>>(
        wout_b, O0, xnT, Lp, out, bout);
}